// Round 1
// 1023.599 us; speedup vs baseline: 1.3590x; 1.3590x over previous
//
#include <hip/hip_runtime.h>
#include <math.h>

// ---------------- workspace layout (float2 units) ----------------
// ws_bs : 24 gates x 576   sector-packed BS:  Gp[j*9 + tt] = U[j][k(tt)]
// ws_g1 : 16 gates x 64    one-mode GT[k*8+j] with interferometer-rotation /
//                          Kerr diagonals PRE-FOLDED (no diag passes in main)
#define WS_G1_OFF   (24*576)

typedef float v2f __attribute__((ext_vector_type(2)));

__device__ __forceinline__ float2 cmul(float2 a, float2 b){
  return make_float2(a.x*b.x - a.y*b.y, a.x*b.y + a.y*b.x);
}

// complex MAC: acc += s*g  via 2x v_pk_fma_f32 (instead of 4 scalar FMA)
//  A: acc.x += s.x*g.x ; acc.y += s.x*g.y        (broadcast s.x via op_sel_hi)
//  B: acc.x += -s.y*g.y ; acc.y += s.y*g.x       (op_sel swap + neg_lo)
__device__ __forceinline__ void cmac(v2f& acc, v2f s, v2f g){
  asm("v_pk_fma_f32 %0, %1, %2, %0 op_sel_hi:[0,1,1]\n\t"
      "v_pk_fma_f32 %0, %1, %2, %0 op_sel:[1,1,0] op_sel_hi:[1,0,1] neg_lo:[1,0,0]"
      : "+v"(acc) : "v"(s), "v"(g));
}

// ---------------- setup: 24 beamsplitter 64x64 expm (unchanged) ----------------
__global__ __launch_bounds__(256) void setup_bs(
    const float* __restrict__ th1, const float* __restrict__ ph1,
    const float* __restrict__ th2, const float* __restrict__ ph2,
    float2* __restrict__ ws)
{
  __shared__ float2 bufA[4096];
  __shared__ float2 bufB[4096];
  const int g = blockIdx.x;          // 0..23
  const int t = threadIdx.x;
  const int l = g/12, intf = (g%12)/6, pos = g%6;
  const float th = (intf ? th2 : th1)[l*6+pos];
  const float ph = (intf ? ph2 : ph1)[l*6+pos];
  float nrm = fabsf(th)*14.0f;                 // row-sum norm bound
  int sq = 0;
  if (nrm > 0.25f) sq = (int)ceilf(log2f(nrm*4.0f));
  const float tc  = th * ldexpf(1.0f, -sq);    // scaled theta
  const float cph = cosf(ph), sph = sinf(ph);

  float2* cur = bufA; float2* nxt = bufB;
  for (int e=0;e<16;e++){ int idx=t*16+e;
    cur[idx] = make_float2(((idx>>6)==(idx&63))?1.f:0.f, 0.f); }
  __syncthreads();
  // Horner Taylor: B = I + Hs*B/k, k=12..1   (Hs applied sparsely: 2 taps/row)
  for (int k=12;k>=1;k--){
    const float inv = 1.0f/(float)k;
    for (int e=0;e<16;e++){
      const int idx=t*16+e; const int row=idx>>6, c=idx&63;
      const int m1=row>>3, m2=row&7;
      float vx=0.f, vy=0.f;
      if (m1<7 && m2>=1){
        const float mag = tc*sqrtf((float)((m1+1)*m2));
        const float2 q = cur[((m1+1)*8+(m2-1))*64 + c];
        vx += mag*(cph*q.x - sph*q.y);
        vy += mag*(cph*q.y + sph*q.x);
      }
      if (m1>=1 && m2<7){
        const float mag = tc*sqrtf((float)(m1*(m2+1)));
        const float2 q = cur[((m1-1)*8+(m2+1))*64 + c];
        vx -= mag*(cph*q.x + sph*q.y);
        vy -= mag*(cph*q.y - sph*q.x);
      }
      vx *= inv; vy *= inv;
      if (row==c) vx += 1.0f;
      nxt[idx] = make_float2(vx,vy);
    }
    __syncthreads();
    float2* tmp=cur; cur=nxt; nxt=tmp;
  }
  // squarings
  for (int si=0; si<sq; si++){
    for (int e=0;e<16;e++){
      const int idx=t*16+e; const int row=idx>>6, c=idx&63;
      float vx=0.f, vy=0.f;
      for (int q=0;q<64;q++){
        const float2 a_ = cur[row*64+q];
        const float2 b_ = cur[q*64+c];
        vx += a_.x*b_.x - a_.y*b_.y;
        vy += a_.x*b_.y + a_.y*b_.x;
      }
      nxt[idx] = make_float2(vx,vy);
    }
    __syncthreads();
    float2* tmp=cur; cur=nxt; nxt=tmp;
  }
  // sector-packed write: for out-pair j=(n1,n2), taps ti=t0..t1, k = 7*ti+N
  for (int e=t; e<576; e+=256){
    const int j = e/9, tt = e%9;
    const int n1=j>>3, n2=j&7, N=n1+n2;
    const int t0 = (N>7)?(N-7):0, t1 = (N<7)?N:7;
    const int ti = t0+tt;
    float2 v = make_float2(0.f,0.f);
    if (ti <= t1){ const int kk = 7*ti + N; v = cur[j*64+kk]; }
    ws[g*576 + e] = v;
  }
}

// ---------------- setup: 16 one-mode 8x8 expm, diagonals folded in ----------------
// squeeze gate (g<8, layer l, mode m):  G'[j][k] = G_sq[j][k] * e^{i varphi1 k}
// disp gate  (g>=8):                    G'[j][k] = e^{i kappa j^2} G_d[j][k] e^{i varphi2 k}
// (per-mode diagonals commute with gates on other modes, so folding is exact)
__global__ __launch_bounds__(128) void setup_small(
    const float* __restrict__ rr,  const float* __restrict__ phr,
    const float* __restrict__ aa,  const float* __restrict__ pha,
    const float* __restrict__ vph1,const float* __restrict__ vph2,
    const float* __restrict__ kap,
    float2* __restrict__ ws_g1)
{
  const int g = blockIdx.x, t = threadIdx.x;   // g: 0..15
  __shared__ float2 h8[64], bufA[64], bufB[64];
  const int isSq = (g < 8);
  const int gi = isSq ? g : (g-8);
  const int li = gi>>2, m = gi&3;
  const float p1 = isSq ? rr[li*4+m]  : aa[li*4+m];
  const float p2 = isSq ? phr[li*4+m] : pha[li*4+m];
  const float nrm = fabsf(p1)*6.0f;
  int sq = 0; if (nrm > 0.25f) sq = (int)ceilf(log2f(nrm*4.0f));
  const float sc = ldexpf(1.0f,-sq);
  const float cp = cosf(p2), sp = sinf(p2);
  if (t < 64){
    const int row=t>>3, c=t&7;
    float2 v = make_float2(0.f,0.f);
    if (isSq){
      if (c == row+2){ const float mg = 0.5f*p1*sqrtf((float)((row+1)*(row+2)));
                       v = make_float2( mg*cp, -mg*sp); }
      else if (c+2 == row){ const float mg = 0.5f*p1*sqrtf((float)((row-1)*row));
                       v = make_float2(-mg*cp, -mg*sp); }
    } else {
      if (c+1 == row){ const float mg = p1*sqrtf((float)row);
                       v = make_float2( mg*cp,  mg*sp); }
      else if (c == row+1){ const float mg = p1*sqrtf((float)(row+1));
                       v = make_float2(-mg*cp,  mg*sp); }
    }
    h8[t]   = make_float2(v.x*sc, v.y*sc);
    bufA[t] = make_float2((row==c)?1.f:0.f, 0.f);
  }
  __syncthreads();
  float2* cur=bufA; float2* nxt=bufB;
  for (int k=12;k>=1;k--){
    const float inv = 1.0f/(float)k;
    if (t<64){
      const int row=t>>3, c=t&7;
      float vx=0.f, vy=0.f;
      for (int q=0;q<8;q++){
        const float2 a_=h8[row*8+q], b_=cur[q*8+c];
        vx += a_.x*b_.x - a_.y*b_.y; vy += a_.x*b_.y + a_.y*b_.x;
      }
      vx*=inv; vy*=inv; if (row==c) vx += 1.f;
      nxt[t]=make_float2(vx,vy);
    }
    __syncthreads();
    float2* tmp=cur; cur=nxt; nxt=tmp;
  }
  for (int si=0; si<sq; si++){
    if (t<64){
      const int row=t>>3, c=t&7;
      float vx=0.f, vy=0.f;
      for (int q=0;q<8;q++){
        const float2 a_=cur[row*8+q], b_=cur[q*8+c];
        vx += a_.x*b_.x - a_.y*b_.y; vy += a_.x*b_.y + a_.y*b_.x;
      }
      nxt[t]=make_float2(vx,vy);
    }
    __syncthreads();
    float2* tmp=cur; cur=nxt; nxt=tmp;
  }
  if (t<64){
    const int kk=t>>3, j=t&7;
    const float2 v = cur[j*8+kk];          // G[j][kk]
    float ang;
    if (isSq) ang = vph1[li*4+m]*(float)kk;
    else      ang = vph2[li*4+m]*(float)kk + kap[li*4+m]*(float)(j*j);
    const float ca = cosf(ang), sa = sinf(ang);
    ws_g1[g*64 + t] = make_float2(v.x*ca - v.y*sa, v.x*sa + v.y*ca);  // GT[k][j]
  }
}

// ---------------- main kernel ----------------
// State in LDS, padded: addr(idx) = idx + (idx>>6).
// Padded strides: i0:520  i1:65  i2:8  i3:1  (exact decomposition)

// Sector-balanced output permutation for bs_gate: group cg handles the 4
// outputs PERM[cg][0..3]. Quads are equal-sector-size (equal tap counts ->
// no masked-lane waste within a wave slot) and per-wave totals are balanced
// (every wave issues exactly 22 tap iterations vs 29.5 before).
#define PW(a,b,c,d) ((unsigned)(a)|((unsigned)(b)<<8)|((unsigned)(c)<<16)|((unsigned)(d)<<24))
__constant__ unsigned PERMW[16] = {
  PW( 0, 4,51, 7), PW(63,11,58,14), PW( 1,18, 6,21), PW( 8,25,13,28),
  PW(55, 3,20,35), PW(62,10,27,42), PW( 2,17,34,49), PW( 9,24,41,56),
  PW(16,32,48,36), PW(47,31,15,43), PW(54,38,22,50), PW(61,45,29,57),
  PW(39,52,19,23), PW(46,59,26,30), PW(53, 5,33,37), PW(60,12,40,44)
};
#undef PW

template<int P>
__device__ __forceinline__ void bs_gate(const float2* __restrict__ Ug,
                                        float2* __restrict__ S,
                                        float2* __restrict__ Gp, int t,
                                        const int* __restrict__ jv,
                                        const int* __restrict__ Nv)
{
  { // float4 staging: 576 float2 = 288 float4
    const float4* __restrict__ u4 = (const float4*)Ug;
    float4* g4 = (float4*)Gp;
    g4[t] = u4[t];
    if (t < 32) g4[256+t] = u4[256+t];
  }
  __syncthreads();
  constexpr int Ac = (P==0)?65:((P==1)?8:1);
  constexpr int Bc = (P==1)?1:0;
  constexpr int Cc = (P==0)?8:520;
  constexpr int Dc = (P==2)?65:1;
  const int rg = t & 15;
  int sbase[4];
#pragma unroll
  for (int i=0;i<4;i++){
    const int spec = rg + 16*i;     // bank-conflict-free lane map
    sbase[i] = Cc*(spec>>3) + Dc*(spec&7);
  }
  v2f acc[4][4];
#pragma unroll
  for (int i=0;i<4;i++)
#pragma unroll
    for (int jj=0;jj<4;jj++) acc[i][jj] = (v2f){0.f,0.f};
#pragma unroll
  for (int jj=0;jj<4;jj++){
    const int j = jv[jj], N = Nv[jj];
    const int t0 = (N>7)?(N-7):0, t1 = (N<7)?N:7;
    const float2* gRow = Gp + j*9 - t0;
    for (int ti=t0; ti<=t1; ti++){          // photon-number sector taps
      const v2f g = *(const v2f*)&gRow[ti];
      const int k = 7*ti + N;
      const int koff = Ac*k + Bc*(k>>3);
#pragma unroll
      for (int i=0;i<4;i++)
        cmac(acc[i][jj], *(const v2f*)&S[sbase[i]+koff], g);
    }
  }
  __syncthreads();
#pragma unroll
  for (int jj=0;jj<4;jj++){
    const int j = jv[jj];
    const int joff = Ac*j + Bc*(j>>3);
#pragma unroll
    for (int i=0;i<4;i++) *(v2f*)&S[sbase[i]+joff] = acc[i][jj];
  }
  __syncthreads();
}

// one-mode gate on mode M. Lane->spectator maps chosen so every 16-lane
// quarter spans all 16 bank pairs (conflict-free ds_read/write_b64):
//  M=0: base = 65*(v>>6) + 8*((v>>3)&7) + (v&7)             ek=520
//  M=1: base = 520*(v>>6) + 8*((v>>3)&7) + (v&7)            ek=65
//  M=2: i0 bits{3,7,8}, i1 bits{4..6}, i3 bits{0..2}        ek=8
//  M=3: i2 bits{3,7,8}, i0 bits{4..6}, i1 bits{0..2}        ek=1
template<int M>
__device__ __forceinline__ void one_mode(const float2* __restrict__ Gg,
                                         float2* __restrict__ S,
                                         float2* __restrict__ Gp, int t)
{
  if (t < 32) ((float4*)Gp)[t] = ((const float4*)Gg)[t];
  __syncthreads();
  constexpr int ek = (M==0)?520:((M==1)?65:((M==2)?8:1));
  int base[2];
#pragma unroll
  for (int vv=0; vv<2; vv++){
    const int v = t + vv*256;
    if      constexpr (M==0) base[vv] = 65*(v>>6) + 8*((v>>3)&7) + (v&7);
    else if constexpr (M==1) base[vv] = 520*(v>>6) + 8*((v>>3)&7) + (v&7);
    else if constexpr (M==2) base[vv] = 520*(((v>>3)&1)|(((v>>7)&3)<<1)) + 65*((v>>4)&7) + (v&7);
    else                     base[vv] = 520*((v>>4)&7) + 65*(v&7) + 8*(((v>>3)&1)|(((v>>7)&3)<<1));
  }
  v2f acc[2][8];
#pragma unroll
  for (int vv=0; vv<2; vv++)
#pragma unroll
    for (int j=0;j<8;j++) acc[vv][j] = (v2f){0.f,0.f};
#pragma unroll
  for (int k=0;k<8;k++){
    const v2f s0 = *(const v2f*)&S[base[0] + ek*k];
    const v2f s1 = *(const v2f*)&S[base[1] + ek*k];
#pragma unroll
    for (int j=0;j<8;j++){
      const v2f g = *(const v2f*)&Gp[k*8+j];
      cmac(acc[0][j], s0, g);
      cmac(acc[1][j], s1, g);
    }
  }
  __syncthreads();
#pragma unroll
  for (int vv=0; vv<2; vv++)
#pragma unroll
    for (int j=0;j<8;j++) *(v2f*)&S[base[vv] + ek*j] = acc[vv][j];
  __syncthreads();
}

__global__ __launch_bounds__(256,4) void qnn_main(
    const float* __restrict__ x, const float2* __restrict__ ws,
    float* __restrict__ out)
{
  __shared__ __align__(16) float2 S[4160];     // 4096 + pad(idx>>6)
  __shared__ __align__(16) float2 Gp[576];     // gate staging / reduction
  const int b = blockIdx.x, t = threadIdx.x;
  const int cg = t>>4;
  const int wv = t>>6;
  const int i2c = (t>>3)&7, i3c = t&7;

  int jv[4], Nv[4];
  { const unsigned pw = PERMW[cg];
#pragma unroll
    for (int jj=0;jj<4;jj++){
      const int j = (int)((pw >> (8*jj)) & 63u);
      jv[jj] = j; Nv[jj] = (j>>3) + (j&7);
    } }

  // coherent columns: c_n = e^{-x^2/2} x^n / sqrt(n!)
  float* colf = (float*)Gp;
  if (t < 32){
    const int m = t>>3, n = t&7;
    const float xv = x[b*4+m];
    float val = expf(-0.5f*xv*xv);
    for (int q=1;q<=n;q++) val *= xv * rsqrtf((float)q);
    colf[t] = val;
  }
  __syncthreads();
  { // lane-contiguous init (conflict-free), idx = e*256 + t
    const float c23 = colf[16+i2c]*colf[24+i3c];
    const float c1a = colf[8+wv], c1b = colf[12+wv];
#pragma unroll
    for (int e=0;e<16;e++){
      const int idx = e*256 + t;
      const float v = colf[e>>1] * ((e&1)?c1b:c1a) * c23;
      S[idx + (idx>>6)] = make_float2(v, 0.f);
    }
  }
  __syncthreads();

  const float2* ws_g1 = ws + WS_G1_OFF;
#pragma unroll 1
  for (int l=0; l<2; l++){
#pragma unroll 1
    for (int r=0; r<2; r++){
      const float2* bsg = ws + (l*12 + r*6)*576;
#pragma unroll 1
      for (int h=0; h<2; h++){
        bs_gate<0>(bsg,       S, Gp, t, jv, Nv);   // pair (0,1)
        bs_gate<2>(bsg+576,   S, Gp, t, jv, Nv);   // pair (2,3)
        bs_gate<1>(bsg+1152,  S, Gp, t, jv, Nv);   // pair (1,2)
        bsg += 3*576;
      }
      const float2* om = ws_g1 + (r*8 + l*4)*64;   // r=0: squeeze', r=1: disp' (diag folded)
      one_mode<0>(om,     S, Gp, t);
      one_mode<1>(om+64,  S, Gp, t);
      one_mode<2>(om+128, S, Gp, t);
      one_mode<3>(om+192, S, Gp, t);
    }
  }

  // <X_i> = 2 Re sum conj(s[n_i]) sqrt(n_i+1) s[n_i+1]   (lane-contiguous map)
  const float w1a = sqrtf((float)(wv+1));
  const float w1b = sqrtf((float)(wv+5));
  const float w2 = sqrtf((float)(i2c+1)), w3 = sqrtf((float)(i3c+1));
  float am0=0.f, am1=0.f, am2=0.f, am3=0.f;
#pragma unroll
  for (int e=0;e<16;e++){
    const int idx = e*256 + t;
    const float2 a = S[idx + (idx>>6)];
    if ((e>>1) < 7){
      const int j2 = idx + 512; const float2 bz = S[j2 + (j2>>6)];
      am0 = fmaf(a.x*bz.x + a.y*bz.y, sqrtf((float)((e>>1)+1)), am0);
    }
    if (((e&1)==0) || (wv<3)){          // i1 = wv + 4*(e&1)
      const int j2 = idx + 64; const float2 bz = S[j2 + (j2>>6)];
      am1 = fmaf(a.x*bz.x + a.y*bz.y, (e&1)?w1b:w1a, am1);
    }
    if (i2c < 7){
      const int j2 = idx + 8; const float2 bz = S[j2 + (j2>>6)];
      am2 = fmaf(a.x*bz.x + a.y*bz.y, w2, am2);
    }
    if (i3c < 7){
      const int j2 = idx + 1; const float2 bz = S[j2 + (j2>>6)];
      am3 = fmaf(a.x*bz.x + a.y*bz.y, w3, am3);
    }
  }
#pragma unroll
  for (int o=32;o;o>>=1){
    am0 += __shfl_down(am0,o,64);
    am1 += __shfl_down(am1,o,64);
    am2 += __shfl_down(am2,o,64);
    am3 += __shfl_down(am3,o,64);
  }
  __syncthreads();
  float* red = (float*)Gp;
  if ((t&63)==0){
    red[wv*4+0]=am0; red[wv*4+1]=am1; red[wv*4+2]=am2; red[wv*4+3]=am3;
  }
  __syncthreads();
  if (t<4) out[b*4+t] = 2.f*(red[t]+red[4+t]+red[8+t]+red[12+t]);
}

// ---------------- host ----------------
extern "C" void kernel_launch(void* const* d_in, const int* in_sizes, int n_in,
                              void* d_out, int out_size, void* d_ws, size_t ws_size,
                              hipStream_t stream)
{
  const float* x    = (const float*)d_in[0];
  const float* th1  = (const float*)d_in[1];
  const float* ph1  = (const float*)d_in[2];
  const float* vph1 = (const float*)d_in[3];
  const float* rr   = (const float*)d_in[4];
  const float* phr  = (const float*)d_in[5];
  const float* th2  = (const float*)d_in[6];
  const float* ph2  = (const float*)d_in[7];
  const float* vph2 = (const float*)d_in[8];
  const float* aa   = (const float*)d_in[9];
  const float* pha  = (const float*)d_in[10];
  const float* kap  = (const float*)d_in[11];
  float2* ws  = (float2*)d_ws;
  float*  out = (float*)d_out;
  const int B = in_sizes[0] / 4;

  hipLaunchKernelGGL(setup_bs, dim3(24), dim3(256), 0, stream, th1, ph1, th2, ph2, ws);
  hipLaunchKernelGGL(setup_small, dim3(16), dim3(128), 0, stream,
                     rr, phr, aa, pha, vph1, vph2, kap, ws + WS_G1_OFF);
  hipLaunchKernelGGL(qnn_main, dim3(B), dim3(256), 0, stream, x, ws, out);
}

// Round 2
// 914.931 us; speedup vs baseline: 1.5204x; 1.1188x over previous
//
#include <hip/hip_runtime.h>
#include <math.h>

// ---------------- workspace layout (float2 units) ----------------
// ws_bs : 24 gates x 384  sector-packed BS: for sector N (size s, row SR=even(s)),
//                         g[SECBASE[N] + o*SR + ti] = U[j_o][k_ti]
// ws_g1 : 16 gates x 64   one-mode GT[k*8+j] with rotation/Kerr diagonals folded
#define WS_G1_OFF   (24*384)

typedef float v2f __attribute__((ext_vector_type(2)));

// complex MAC: acc += s*g  via 2x v_pk_fma_f32
__device__ __forceinline__ void cmac(v2f& acc, v2f s, v2f g){
  asm("v_pk_fma_f32 %0, %1, %2, %0 op_sel_hi:[0,1,1]\n\t"
      "v_pk_fma_f32 %0, %1, %2, %0 op_sel:[1,1,0] op_sel_hi:[1,0,1] neg_lo:[1,0,0]"
      : "+v"(acc) : "v"(s), "v"(g));
}

// ---------------- setup: 24 beamsplitter 64x64 expm ----------------
__global__ __launch_bounds__(256) void setup_bs(
    const float* __restrict__ th1, const float* __restrict__ ph1,
    const float* __restrict__ th2, const float* __restrict__ ph2,
    float2* __restrict__ ws)
{
  __shared__ float2 bufA[4096];
  __shared__ float2 bufB[4096];
  const int g = blockIdx.x;          // 0..23
  const int t = threadIdx.x;
  const int l = g/12, intf = (g%12)/6, pos = g%6;
  const float th = (intf ? th2 : th1)[l*6+pos];
  const float ph = (intf ? ph2 : ph1)[l*6+pos];
  float nrm = fabsf(th)*14.0f;                 // row-sum norm bound
  int sq = 0;
  if (nrm > 0.25f) sq = (int)ceilf(log2f(nrm*4.0f));
  const float tc  = th * ldexpf(1.0f, -sq);    // scaled theta
  const float cph = cosf(ph), sph = sinf(ph);

  float2* cur = bufA; float2* nxt = bufB;
  for (int e=0;e<16;e++){ int idx=t*16+e;
    cur[idx] = make_float2(((idx>>6)==(idx&63))?1.f:0.f, 0.f); }
  __syncthreads();
  // Horner Taylor: B = I + Hs*B/k, k=12..1   (Hs applied sparsely: 2 taps/row)
  for (int k=12;k>=1;k--){
    const float inv = 1.0f/(float)k;
    for (int e=0;e<16;e++){
      const int idx=t*16+e; const int row=idx>>6, c=idx&63;
      const int m1=row>>3, m2=row&7;
      float vx=0.f, vy=0.f;
      if (m1<7 && m2>=1){
        const float mag = tc*sqrtf((float)((m1+1)*m2));
        const float2 q = cur[((m1+1)*8+(m2-1))*64 + c];
        vx += mag*(cph*q.x - sph*q.y);
        vy += mag*(cph*q.y + sph*q.x);
      }
      if (m1>=1 && m2<7){
        const float mag = tc*sqrtf((float)(m1*(m2+1)));
        const float2 q = cur[((m1-1)*8+(m2+1))*64 + c];
        vx -= mag*(cph*q.x + sph*q.y);
        vy -= mag*(cph*q.y - sph*q.x);
      }
      vx *= inv; vy *= inv;
      if (row==c) vx += 1.0f;
      nxt[idx] = make_float2(vx,vy);
    }
    __syncthreads();
    float2* tmp=cur; cur=nxt; nxt=tmp;
  }
  // squarings
  for (int si=0; si<sq; si++){
    for (int e=0;e<16;e++){
      const int idx=t*16+e; const int row=idx>>6, c=idx&63;
      float vx=0.f, vy=0.f;
      for (int q=0;q<64;q++){
        const float2 a_ = cur[row*64+q];
        const float2 b_ = cur[q*64+c];
        vx += a_.x*b_.x - a_.y*b_.y;
        vy += a_.x*b_.y + a_.y*b_.x;
      }
      nxt[idx] = make_float2(vx,vy);
    }
    __syncthreads();
    float2* tmp=cur; cur=nxt; nxt=tmp;
  }
  // sector-packed write: enumerate (N, o, ti-with-row-pad) linearly over 384 slots
  for (int e=t; e<384; e+=256){
    int rem = e, N = 0, S_=0, SR_=0;
    for (; N<15; N++){
      S_  = 8 - ((N<7)?(7-N):(N-7));
      SR_ = (S_+1)&~1;
      if (rem < S_*SR_) break;
      rem -= S_*SR_;
    }
    float2 v = make_float2(0.f,0.f);
    if (N < 15){
      const int o = rem / SR_, ti = rem % SR_;
      if (ti < S_){
        const int T0 = (N>7)?(N-7):0;
        const int j = 7*(T0+o)+N, k = 7*(T0+ti)+N;
        v = cur[j*64 + k];
      }
    }
    ws[g*384 + e] = v;
  }
}

// ---------------- setup: 16 one-mode 8x8 expm, diagonals folded in ----------------
__global__ __launch_bounds__(128) void setup_small(
    const float* __restrict__ rr,  const float* __restrict__ phr,
    const float* __restrict__ aa,  const float* __restrict__ pha,
    const float* __restrict__ vph1,const float* __restrict__ vph2,
    const float* __restrict__ kap,
    float2* __restrict__ ws_g1)
{
  const int g = blockIdx.x, t = threadIdx.x;   // g: 0..15
  __shared__ float2 h8[64], bufA[64], bufB[64];
  const int isSq = (g < 8);
  const int gi = isSq ? g : (g-8);
  const int li = gi>>2, m = gi&3;
  const float p1 = isSq ? rr[li*4+m]  : aa[li*4+m];
  const float p2 = isSq ? phr[li*4+m] : pha[li*4+m];
  const float nrm = fabsf(p1)*6.0f;
  int sq = 0; if (nrm > 0.25f) sq = (int)ceilf(log2f(nrm*4.0f));
  const float sc = ldexpf(1.0f,-sq);
  const float cp = cosf(p2), sp = sinf(p2);
  if (t < 64){
    const int row=t>>3, c=t&7;
    float2 v = make_float2(0.f,0.f);
    if (isSq){
      if (c == row+2){ const float mg = 0.5f*p1*sqrtf((float)((row+1)*(row+2)));
                       v = make_float2( mg*cp, -mg*sp); }
      else if (c+2 == row){ const float mg = 0.5f*p1*sqrtf((float)((row-1)*row));
                       v = make_float2(-mg*cp, -mg*sp); }
    } else {
      if (c+1 == row){ const float mg = p1*sqrtf((float)row);
                       v = make_float2( mg*cp,  mg*sp); }
      else if (c == row+1){ const float mg = p1*sqrtf((float)(row+1));
                       v = make_float2(-mg*cp,  mg*sp); }
    }
    h8[t]   = make_float2(v.x*sc, v.y*sc);
    bufA[t] = make_float2((row==c)?1.f:0.f, 0.f);
  }
  __syncthreads();
  float2* cur=bufA; float2* nxt=bufB;
  for (int k=12;k>=1;k--){
    const float inv = 1.0f/(float)k;
    if (t<64){
      const int row=t>>3, c=t&7;
      float vx=0.f, vy=0.f;
      for (int q=0;q<8;q++){
        const float2 a_=h8[row*8+q], b_=cur[q*8+c];
        vx += a_.x*b_.x - a_.y*b_.y; vy += a_.x*b_.y + a_.y*b_.x;
      }
      vx*=inv; vy*=inv; if (row==c) vx += 1.f;
      nxt[t]=make_float2(vx,vy);
    }
    __syncthreads();
    float2* tmp=cur; cur=nxt; nxt=tmp;
  }
  for (int si=0; si<sq; si++){
    if (t<64){
      const int row=t>>3, c=t&7;
      float vx=0.f, vy=0.f;
      for (int q=0;q<8;q++){
        const float2 a_=cur[row*8+q], b_=cur[q*8+c];
        vx += a_.x*b_.x - a_.y*b_.y; vy += a_.x*b_.y + a_.y*b_.x;
      }
      nxt[t]=make_float2(vx,vy);
    }
    __syncthreads();
    float2* tmp=cur; cur=nxt; nxt=tmp;
  }
  if (t<64){
    const int kk=t>>3, j=t&7;
    const float2 v = cur[j*8+kk];          // G[j][kk]
    float ang;
    if (isSq) ang = vph1[li*4+m]*(float)kk;
    else      ang = vph2[li*4+m]*(float)kk + kap[li*4+m]*(float)(j*j);
    const float ca = cosf(ang), sa = sinf(ang);
    ws_g1[g*64 + t] = make_float2(v.x*ca - v.y*sa, v.x*sa + v.y*ca);  // GT[k][j]
  }
}

// ---------------- main kernel ----------------
// State in LDS, padded: addr(idx) = idx + (idx>>6) -> strides i0:520 i1:65 i2:8 i3:1.
// bs_gate: lane = spectator (all 64); each wave owns disjoint photon-number sectors.
// Per sector: read s taps once (ds_read_b64, conflict-free), accumulate s outputs
// (gates come in via uniform/scalar loads from global), write s outputs. One barrier.

// sector offsets (row-padded prefix sums): N0..N14
//  0,2,6,18,34,64,100,156,220,276,312,342,358,370,374

template<int NN>
__device__ __forceinline__ void bs_sector(const float2* __restrict__ gsec,
                                          float2* __restrict__ Sm,
                                          int sb, int Ac, int Bc)
{
  constexpr int S_ = 8 - ((NN<7)?(7-NN):(NN-7));
  constexpr int T0 = (NN>7)?(NN-7):0;
  constexpr int SR = (S_+1)&~1;
  int ka[S_];
  v2f sv[S_];
#pragma unroll
  for (int i=0;i<S_;i++){
    const int k = 7*(T0+i)+NN;
    ka[i] = sb + Ac*k + Bc*(k>>3);
    sv[i] = *(const v2f*)&Sm[ka[i]];
  }
#pragma unroll
  for (int o=0;o<S_;o++){
    v2f acc = (v2f){0.f,0.f};
#pragma unroll
    for (int i=0;i<S_;i++){
      const v2f g = *(const v2f*)&gsec[o*SR+i];   // uniform address -> scalar path
      cmac(acc, sv[i], g);
    }
    *(v2f*)&Sm[ka[o]] = acc;
  }
}

__device__ __forceinline__ void bs_gate(const float2* __restrict__ gb,
                                        float2* __restrict__ Sm,
                                        int sb, int Ac, int Bc, int wvu)
{
  // per-wave sector lists, cmac-balanced: 85 / 84 / 87 / 88
  if (wvu==0){
    bs_sector<7 >(gb+156, Sm, sb, Ac, Bc);
    bs_sector<3 >(gb+18,  Sm, sb, Ac, Bc);
    bs_sector<13>(gb+370, Sm, sb, Ac, Bc);
    bs_sector<0 >(gb+0,   Sm, sb, Ac, Bc);
  } else if (wvu==1){
    bs_sector<6 >(gb+100, Sm, sb, Ac, Bc);
    bs_sector<4 >(gb+34,  Sm, sb, Ac, Bc);
    bs_sector<2 >(gb+6,   Sm, sb, Ac, Bc);
    bs_sector<14>(gb+374, Sm, sb, Ac, Bc);
  } else if (wvu==2){
    bs_sector<8 >(gb+220, Sm, sb, Ac, Bc);
    bs_sector<10>(gb+312, Sm, sb, Ac, Bc);
    bs_sector<12>(gb+358, Sm, sb, Ac, Bc);
    bs_sector<1 >(gb+2,   Sm, sb, Ac, Bc);
  } else {
    bs_sector<5 >(gb+64,  Sm, sb, Ac, Bc);
    bs_sector<9 >(gb+276, Sm, sb, Ac, Bc);
    bs_sector<11>(gb+342, Sm, sb, Ac, Bc);
  }
  __syncthreads();
}

// one-mode gate on mode M; gate rows fetched via uniform loads (scalar path),
// line-exclusive per thread -> single trailing barrier.
__device__ __forceinline__ void one_mode(int M, const float2* __restrict__ gb,
                                         float2* __restrict__ Sm, int t)
{
  int base[2];
#pragma unroll
  for (int vv=0; vv<2; vv++){
    const int v = t + vv*256;
    int bb;
    if (M==0)      bb = 65*(v>>6) + 8*((v>>3)&7) + (v&7);
    else if (M==1) bb = 520*(v>>6) + 8*((v>>3)&7) + (v&7);
    else if (M==2) bb = 520*(((v>>3)&1)|(((v>>7)&3)<<1)) + 65*((v>>4)&7) + (v&7);
    else           bb = 520*((v>>4)&7) + 65*(v&7) + 8*(((v>>3)&1)|(((v>>7)&3)<<1));
    base[vv] = bb;
  }
  const int ek = (M==0)?520:((M==1)?65:((M==2)?8:1));
  v2f acc[2][8];
#pragma unroll
  for (int vv=0; vv<2; vv++)
#pragma unroll
    for (int j=0;j<8;j++) acc[vv][j] = (v2f){0.f,0.f};
#pragma unroll
  for (int k=0;k<8;k++){
    const v2f sA = *(const v2f*)&Sm[base[0] + ek*k];
    const v2f sB = *(const v2f*)&Sm[base[1] + ek*k];
#pragma unroll
    for (int j=0;j<8;j++){
      const v2f g = *(const v2f*)&gb[k*8+j];      // uniform -> scalar path
      cmac(acc[0][j], sA, g);
      cmac(acc[1][j], sB, g);
    }
  }
#pragma unroll
  for (int vv=0; vv<2; vv++)
#pragma unroll
    for (int j=0;j<8;j++) *(v2f*)&Sm[base[vv] + ek*j] = acc[vv][j];
  __syncthreads();
}

__global__ __launch_bounds__(256,4) void qnn_main(
    const float* __restrict__ x, const float2* __restrict__ ws,
    float* __restrict__ out)
{
  __shared__ __align__(16) float2 S[4160];     // 4096 + pad(idx>>6)
  __shared__ float colf[32];
  __shared__ float red[16];
  const int b = blockIdx.x, t = threadIdx.x;
  const int lane = t & 63;
  const int wvu = __builtin_amdgcn_readfirstlane(t>>6);   // provably-uniform wave id
  const int i2c = (t>>3)&7, i3c = t&7;

  // coherent columns: c_n = e^{-x^2/2} x^n / sqrt(n!)
  if (t < 32){
    const int m = t>>3, n = t&7;
    const float xv = x[b*4+m];
    float val = expf(-0.5f*xv*xv);
    for (int q=1;q<=n;q++) val *= xv * rsqrtf((float)q);
    colf[t] = val;
  }
  __syncthreads();
  { // lane-contiguous init (conflict-free), idx = e*256 + t
    const float c23 = colf[16+i2c]*colf[24+i3c];
    const float c1a = colf[8+wvu], c1b = colf[12+wvu];
#pragma unroll
    for (int e=0;e<16;e++){
      const int idx = e*256 + t;
      const float v = colf[e>>1] * ((e&1)?c1b:c1a) * c23;
      S[idx + (idx>>6)] = make_float2(v, 0.f);
    }
  }
  __syncthreads();

  // spectator bases per pair map (bank-pair-complete per 16-lane phase group)
  const int sbP0 = lane;                               // pair (0,1): spec=(i2,i3)
  const int sbP1 = 520*(lane>>3) + (lane&7);           // pair (1,2): spec=(i0,i3)
  const int sbP2 = 520*(lane>>3) + 65*(lane&7);        // pair (2,3): spec=(i0,i1)
  const float2* ws_g1 = ws + WS_G1_OFF;

#pragma unroll 1
  for (int seg=0; seg<4; seg++){                       // seg = l*2 + r
    const float2* bsg = ws + seg*(6*384);
#pragma unroll 1
    for (int q=0; q<6; q++){                           // pair pattern 0,2,1,0,2,1
      const int pm = (q>=3)? (q-3) : q;
      int sb, Ac, Bc;
      if (pm==0){ sb=sbP0; Ac=65; Bc=0; }
      else if (pm==1){ sb=sbP2; Ac=1; Bc=0; }
      else { sb=sbP1; Ac=8; Bc=1; }
      bs_gate(bsg + q*384, S, sb, Ac, Bc, wvu);
    }
    const int l = seg>>1, r = seg&1;
    const float2* om = ws_g1 + (r*8 + l*4)*64;         // r=0: squeeze', r=1: disp'
#pragma unroll 1
    for (int m=0;m<4;m++) one_mode(m, om + m*64, S, t);
  }

  // <X_i> = 2 Re sum conj(s[n_i]) sqrt(n_i+1) s[n_i+1]   (lane-contiguous map)
  const float w1a = sqrtf((float)(wvu+1));
  const float w1b = sqrtf((float)(wvu+5));
  const float w2 = sqrtf((float)(i2c+1)), w3 = sqrtf((float)(i3c+1));
  float am0=0.f, am1=0.f, am2=0.f, am3=0.f;
#pragma unroll
  for (int e=0;e<16;e++){
    const int idx = e*256 + t;
    const float2 a = S[idx + (idx>>6)];
    if ((e>>1) < 7){
      const int j2 = idx + 512; const float2 bz = S[j2 + (j2>>6)];
      am0 = fmaf(a.x*bz.x + a.y*bz.y, sqrtf((float)((e>>1)+1)), am0);
    }
    if (((e&1)==0) || (wvu<3)){          // i1 = wvu + 4*(e&1)
      const int j2 = idx + 64; const float2 bz = S[j2 + (j2>>6)];
      am1 = fmaf(a.x*bz.x + a.y*bz.y, (e&1)?w1b:w1a, am1);
    }
    if (i2c < 7){
      const int j2 = idx + 8; const float2 bz = S[j2 + (j2>>6)];
      am2 = fmaf(a.x*bz.x + a.y*bz.y, w2, am2);
    }
    if (i3c < 7){
      const int j2 = idx + 1; const float2 bz = S[j2 + (j2>>6)];
      am3 = fmaf(a.x*bz.x + a.y*bz.y, w3, am3);
    }
  }
#pragma unroll
  for (int o=32;o;o>>=1){
    am0 += __shfl_down(am0,o,64);
    am1 += __shfl_down(am1,o,64);
    am2 += __shfl_down(am2,o,64);
    am3 += __shfl_down(am3,o,64);
  }
  __syncthreads();
  if ((t&63)==0){
    red[wvu*4+0]=am0; red[wvu*4+1]=am1; red[wvu*4+2]=am2; red[wvu*4+3]=am3;
  }
  __syncthreads();
  if (t<4) out[b*4+t] = 2.f*(red[t]+red[4+t]+red[8+t]+red[12+t]);
}

// ---------------- host ----------------
extern "C" void kernel_launch(void* const* d_in, const int* in_sizes, int n_in,
                              void* d_out, int out_size, void* d_ws, size_t ws_size,
                              hipStream_t stream)
{
  const float* x    = (const float*)d_in[0];
  const float* th1  = (const float*)d_in[1];
  const float* ph1  = (const float*)d_in[2];
  const float* vph1 = (const float*)d_in[3];
  const float* rr   = (const float*)d_in[4];
  const float* phr  = (const float*)d_in[5];
  const float* th2  = (const float*)d_in[6];
  const float* ph2  = (const float*)d_in[7];
  const float* vph2 = (const float*)d_in[8];
  const float* aa   = (const float*)d_in[9];
  const float* pha  = (const float*)d_in[10];
  const float* kap  = (const float*)d_in[11];
  float2* ws  = (float2*)d_ws;
  float*  out = (float*)d_out;
  const int B = in_sizes[0] / 4;

  hipLaunchKernelGGL(setup_bs, dim3(24), dim3(256), 0, stream, th1, ph1, th2, ph2, ws);
  hipLaunchKernelGGL(setup_small, dim3(16), dim3(128), 0, stream,
                     rr, phr, aa, pha, vph1, vph2, kap, ws + WS_G1_OFF);
  hipLaunchKernelGGL(qnn_main, dim3(B), dim3(256), 0, stream, x, ws, out);
}